// Round 2
// baseline (583.291 us; speedup 1.0000x reference)
//
#include <hip/hip_runtime.h>

#define NN 50000
#define NE 800000

// ws layout (float-index offsets)
#define OFF_SE    0LL               // NN*16 f32   (layer-1 edge-attr sums, reused in layer 2)
#define OFF_H     (16LL*NN)         // NN*64 f32   (hidden after BN+ReLU)
#define OFF_Y2    (80LL*NN)         // NN*32 f32   (H @ W2_msg[0:64,:])
#define OFF_CNT   (112LL*NN)        // NN ints     (dst histogram = degree)
#define OFF_ROW   (113LL*NN)        // NN+1 ints   (CSR row_ptr by dst)
#define OFF_CUR   (115LL*NN)        // NN ints     (fill cursors)
#define OFF_RECS  (116LL*NN)        // NE int2     (src, edge_id) sorted by dst
#define OFF_FLAGS (148LL*NN)        // 2 ints

__device__ __forceinline__ float ldf(const void* p, long long i, int bf16) {
  if (bf16) {
    unsigned short u = ((const unsigned short*)p)[i];
    return __uint_as_float(((unsigned)u) << 16);
  }
  return ((const float*)p)[i];
}

__device__ __forceinline__ unsigned short f2bf(float f) {
  unsigned u = __float_as_uint(f);
  unsigned r = (u + 0x7fffu + ((u >> 16) & 1u)) >> 16;
  return (unsigned short)r;
}

__device__ __forceinline__ int ldidx(const void* p, long long i, int i64) {
  return i64 ? (int)((const long long*)p)[i] : ((const int*)p)[i];
}

__device__ __forceinline__ float bcast(float v, int k) {
  return __uint_as_float(__builtin_amdgcn_readlane(__float_as_uint(v), k));
}

// ---------------- detect dtypes ----------------
__global__ void k_detect(const void* ei, const void* x, int* flags) {
  if (blockIdx.x == 0 && threadIdx.x == 0) {
    const int* p = (const int*)ei;
    int any = 0;
    for (int i = 0; i < 256; ++i) any |= p[2 * i + 1];
    flags[0] = (any == 0) ? 1 : 0;
    const unsigned short* q = (const unsigned short*)x;
    int cnt = 0;
    for (int i = 0; i < 256; ++i) {
      unsigned short w = q[2 * i];
      int e = (w >> 7) & 0xff;
      if (w == 0 || (e >= 110 && e <= 140)) cnt++;
    }
    flags[1] = (cnt >= 192) ? 1 : 0;
  }
}

// ---------------- CSR build: histogram of dst ----------------
__global__ __launch_bounds__(256) void k_hist(const void* __restrict__ ei,
                                              const int* __restrict__ flags,
                                              int* __restrict__ counts) {
  long long e = (long long)blockIdx.x * 256 + threadIdx.x;
  if (e >= NE) return;
  int dst = ldidx(ei, NE + e, flags[0]);
  atomicAdd(&counts[dst], 1);
}

// ---------------- CSR build: exclusive scan (single block) ----------------
__global__ __launch_bounds__(1024) void k_scan(const int* __restrict__ counts,
                                               int* __restrict__ row_ptr,
                                               int* __restrict__ cursor) {
  __shared__ int sd[1024];
  const int CH = 49;  // 1024*49 >= 50000
  int t = threadIdx.x;
  int beg = t * CH;
  int end = beg + CH;
  if (beg > NN) beg = NN;
  if (end > NN) end = NN;
  int s = 0;
  for (int i = beg; i < end; ++i) s += counts[i];
  sd[t] = s;
  __syncthreads();
  for (int off = 1; off < 1024; off <<= 1) {
    int v = (t >= off) ? sd[t - off] : 0;
    __syncthreads();
    sd[t] += v;
    __syncthreads();
  }
  int run = sd[t] - s;  // exclusive prefix
  for (int i = beg; i < end; ++i) {
    row_ptr[i] = run;
    cursor[i] = run;
    run += counts[i];
  }
  if (t == 1023) row_ptr[NN] = run;
}

// ---------------- CSR build: fill (src, eid) records ----------------
__global__ __launch_bounds__(256) void k_fill(const void* __restrict__ ei,
                                              const int* __restrict__ flags,
                                              int* __restrict__ cursor,
                                              int2* __restrict__ recs) {
  long long e = (long long)blockIdx.x * 256 + threadIdx.x;
  if (e >= NE) return;
  int i64 = flags[0];
  int src = ldidx(ei, e, i64);
  int dst = ldidx(ei, NE + e, i64);
  int pos = atomicAdd(&cursor[dst], 1);
  recs[pos] = make_int2(src, (int)e);
}

// ---------------- layer 1: fused CSR gather + node GEMM + BN + ReLU ----------------
__global__ __launch_bounds__(256) void k_node1(
    const void* __restrict__ x, const int* __restrict__ row_ptr,
    const int2* __restrict__ recs, const void* __restrict__ ea,
    const void* __restrict__ W1_msg, const void* __restrict__ b1_msg,
    const void* __restrict__ W1_self, const void* __restrict__ b1_self,
    const void* __restrict__ gamma, const void* __restrict__ beta,
    const void* __restrict__ mean, const void* __restrict__ var,
    const int* __restrict__ flags, float* __restrict__ H, float* __restrict__ SeW) {
  int lane = threadIdx.x & 63;
  int bf = flags[1];
  float wself[64], wx[64], we[16];
#pragma unroll
  for (int k = 0; k < 64; ++k) wself[k] = ldf(W1_self, k * 64 + lane, bf);
#pragma unroll
  for (int k = 0; k < 64; ++k) wx[k] = ldf(W1_msg, k * 64 + lane, bf);
#pragma unroll
  for (int k = 0; k < 16; ++k) we[k] = ldf(W1_msg, (64 + k) * 64 + lane, bf);
  float bmsg = ldf(b1_msg, lane, bf);
  float bself = ldf(b1_self, lane, bf);
  float g = ldf(gamma, lane, bf), bt = ldf(beta, lane, bf);
  float mn = ldf(mean, lane, bf), vr = ldf(var, lane, bf);
  float scale = g * rsqrtf(vr + 1e-5f);
  float shift = bt - mn * scale;

  long long nwaves = ((long long)gridDim.x * blockDim.x) >> 6;
  for (long long n = ((long long)blockIdx.x * blockDim.x + threadIdx.x) >> 6; n < NN;
       n += nwaves) {
    int beg = row_ptr[n], end = row_ptr[n + 1];
    float sx = 0.f, se = 0.f;
    for (int base = beg; base < end; base += 64) {
      int m = end - base;
      if (m > 64) m = 64;
      int2 r = recs[base + (lane < m ? lane : 0)];
      int j = 0;
      for (; j + 1 < m; j += 2) {
        int s0 = __builtin_amdgcn_readlane(r.x, j);
        int e0 = __builtin_amdgcn_readlane(r.y, j);
        int s1 = __builtin_amdgcn_readlane(r.x, j + 1);
        int e1 = __builtin_amdgcn_readlane(r.y, j + 1);
        float xa = ldf(x, (long long)s0 * 64 + lane, bf);
        float xb = ldf(x, (long long)s1 * 64 + lane, bf);
        sx += xa + xb;
        if (lane < 16) {
          float ea0 = ldf(ea, (long long)e0 * 16 + lane, bf);
          float ea1 = ldf(ea, (long long)e1 * 16 + lane, bf);
          se += ea0 + ea1;
        }
      }
      if (j < m) {
        int s0 = __builtin_amdgcn_readlane(r.x, j);
        int e0 = __builtin_amdgcn_readlane(r.y, j);
        sx += ldf(x, (long long)s0 * 64 + lane, bf);
        if (lane < 16) se += ldf(ea, (long long)e0 * 16 + lane, bf);
      }
    }
    float dg = (float)(end - beg);
    float xv = ldf(x, n * 64 + lane, bf);
    float a0 = fmaf(dg, bmsg, bself), a1 = 0.f, a2 = 0.f, a3 = 0.f;
#pragma unroll
    for (int k = 0; k < 64; k += 4) {
      a0 = fmaf(bcast(xv, k + 0), wself[k + 0], fmaf(bcast(sx, k + 0), wx[k + 0], a0));
      a1 = fmaf(bcast(xv, k + 1), wself[k + 1], fmaf(bcast(sx, k + 1), wx[k + 1], a1));
      a2 = fmaf(bcast(xv, k + 2), wself[k + 2], fmaf(bcast(sx, k + 2), wx[k + 2], a2));
      a3 = fmaf(bcast(xv, k + 3), wself[k + 3], fmaf(bcast(sx, k + 3), wx[k + 3], a3));
    }
#pragma unroll
    for (int k = 0; k < 16; k += 4) {
      a0 = fmaf(bcast(se, k + 0), we[k + 0], a0);
      a1 = fmaf(bcast(se, k + 1), we[k + 1], a1);
      a2 = fmaf(bcast(se, k + 2), we[k + 2], a2);
      a3 = fmaf(bcast(se, k + 3), we[k + 3], a3);
    }
    float h = (a0 + a1) + (a2 + a3);
    h = fmaf(h, scale, shift);
    h = fmaxf(h, 0.0f);
    H[n * 64 + lane] = h;
    if (lane < 16) SeW[n * 16 + lane] = se;
  }
}

// ---------------- project Y2 = H @ W2_msg[0:64,:]  (N x 32) ----------------
__global__ __launch_bounds__(256) void k_projY2(const float* __restrict__ H,
                                                const void* __restrict__ W2_msg,
                                                const int* __restrict__ flags,
                                                float* __restrict__ Y2) {
  int lane = threadIdx.x & 63;
  int bf = flags[1];
  int j = lane & 31;
  float w[64];
#pragma unroll
  for (int k = 0; k < 64; ++k) w[k] = ldf(W2_msg, k * 32 + j, bf);
  long long nwaves = ((long long)gridDim.x * blockDim.x) >> 6;
  for (long long n = ((long long)blockIdx.x * blockDim.x + threadIdx.x) >> 6; n < NN;
       n += nwaves) {
    float hv = H[n * 64 + lane];
    float a0 = 0.f, a1 = 0.f, a2 = 0.f, a3 = 0.f;
#pragma unroll
    for (int k = 0; k < 64; k += 4) {
      a0 = fmaf(bcast(hv, k + 0), w[k + 0], a0);
      a1 = fmaf(bcast(hv, k + 1), w[k + 1], a1);
      a2 = fmaf(bcast(hv, k + 2), w[k + 2], a2);
      a3 = fmaf(bcast(hv, k + 3), w[k + 3], a3);
    }
    if (lane < 32) Y2[n * 32 + j] = (a0 + a1) + (a2 + a3);
  }
}

// ---------------- layer 2: fused CSR gather of Y2 + node GEMM -> out ----------------
__global__ __launch_bounds__(256) void k_node2(
    const float* __restrict__ H, const float* __restrict__ SeW,
    const int* __restrict__ row_ptr, const int2* __restrict__ recs,
    const float* __restrict__ Y2, const void* __restrict__ W2_msg,
    const void* __restrict__ b2_msg, const void* __restrict__ W2_self,
    const void* __restrict__ b2_self, const int* __restrict__ flags,
    void* __restrict__ out) {
  int lane = threadIdx.x & 63;
  int bf = flags[1];
  int j = lane & 31;
  int half = lane >> 5;
  float wself[64], we[16];
#pragma unroll
  for (int k = 0; k < 64; ++k) wself[k] = ldf(W2_self, k * 32 + j, bf);
#pragma unroll
  for (int k = 0; k < 16; ++k) we[k] = ldf(W2_msg, (64 + k) * 32 + j, bf);
  float bm = ldf(b2_msg, j, bf);
  float bs = ldf(b2_self, j, bf);
  long long nwaves = ((long long)gridDim.x * blockDim.x) >> 6;
  for (long long n = ((long long)blockIdx.x * blockDim.x + threadIdx.x) >> 6; n < NN;
       n += nwaves) {
    int beg = row_ptr[n], end = row_ptr[n + 1];
    float s2 = 0.f;
    for (int base = beg; base < end; base += 64) {
      int m = end - base;
      if (m > 64) m = 64;
      int2 r = recs[base + (lane < m ? lane : 0)];
      int jj = 0;
      for (; jj + 1 < m; jj += 2) {  // halves process alternating edges
        int s0 = __builtin_amdgcn_readlane(r.x, jj);
        int s1 = __builtin_amdgcn_readlane(r.x, jj + 1);
        int ss = half ? s1 : s0;
        s2 += Y2[(long long)ss * 32 + j];
      }
      if (jj < m && half == 0) {
        int s0 = __builtin_amdgcn_readlane(r.x, jj);
        s2 += Y2[(long long)s0 * 32 + j];
      }
    }
    s2 += __shfl_xor(s2, 32, 64);  // combine halves; both halves get full sum
    float hv = H[n * 64 + lane];
    float se = (lane < 16) ? SeW[n * 16 + lane] : 0.0f;
    float dg = (float)(end - beg);
    float a0 = fmaf(dg, bm, bs) + s2;
    float a1 = 0.f, a2 = 0.f, a3 = 0.f;
#pragma unroll
    for (int k = 0; k < 64; k += 4) {
      a0 = fmaf(bcast(hv, k + 0), wself[k + 0], a0);
      a1 = fmaf(bcast(hv, k + 1), wself[k + 1], a1);
      a2 = fmaf(bcast(hv, k + 2), wself[k + 2], a2);
      a3 = fmaf(bcast(hv, k + 3), wself[k + 3], a3);
    }
#pragma unroll
    for (int k = 0; k < 16; k += 4) {
      a0 = fmaf(bcast(se, k + 0), we[k + 0], a0);
      a1 = fmaf(bcast(se, k + 1), we[k + 1], a1);
      a2 = fmaf(bcast(se, k + 2), we[k + 2], a2);
      a3 = fmaf(bcast(se, k + 3), we[k + 3], a3);
    }
    float o = (a0 + a1) + (a2 + a3);
    if (lane < 32) {
      if (bf)
        ((unsigned short*)out)[n * 32 + j] = f2bf(o);
      else
        ((float*)out)[n * 32 + j] = o;
    }
  }
}

extern "C" void kernel_launch(void* const* d_in, const int* in_sizes, int n_in,
                              void* d_out, int out_size, void* d_ws, size_t ws_size,
                              hipStream_t stream) {
  const void* x = d_in[0];
  const void* ei = d_in[1];
  const void* ea = d_in[2];
  const void* W1_msg = d_in[3];
  const void* b1_msg = d_in[4];
  const void* W1_self = d_in[5];
  const void* b1_self = d_in[6];
  const void* gamma = d_in[7];
  const void* beta = d_in[8];
  const void* mean = d_in[9];
  const void* var = d_in[10];
  const void* W2_msg = d_in[11];
  const void* b2_msg = d_in[12];
  const void* W2_self = d_in[13];
  const void* b2_self = d_in[14];

  float* ws = (float*)d_ws;
  float* SeW = ws + OFF_SE;
  float* H = ws + OFF_H;
  float* Y2 = ws + OFF_Y2;
  int* counts = (int*)(ws + OFF_CNT);
  int* row_ptr = (int*)(ws + OFF_ROW);
  int* cursor = (int*)(ws + OFF_CUR);
  int2* recs = (int2*)(ws + OFF_RECS);
  int* flags = (int*)(ws + OFF_FLAGS);

  hipLaunchKernelGGL(k_detect, dim3(1), dim3(64), 0, stream, ei, x, flags);
  hipMemsetAsync(counts, 0, (size_t)NN * sizeof(int), stream);

  int eblocks = (NE + 255) / 256;
  hipLaunchKernelGGL(k_hist, dim3(eblocks), dim3(256), 0, stream, ei, flags, counts);
  hipLaunchKernelGGL(k_scan, dim3(1), dim3(1024), 0, stream, counts, row_ptr, cursor);
  hipLaunchKernelGGL(k_fill, dim3(eblocks), dim3(256), 0, stream, ei, flags, cursor, recs);

  hipLaunchKernelGGL(k_node1, dim3(1024), dim3(256), 0, stream, x, row_ptr, recs, ea,
                     W1_msg, b1_msg, W1_self, b1_self, gamma, beta, mean, var, flags, H,
                     SeW);
  hipLaunchKernelGGL(k_projY2, dim3(1024), dim3(256), 0, stream, H, W2_msg, flags, Y2);
  hipLaunchKernelGGL(k_node2, dim3(1024), dim3(256), 0, stream, H, SeW, row_ptr, recs,
                     Y2, W2_msg, b2_msg, W2_self, b2_self, flags, d_out);
}